// Round 5
// baseline (2739.597 us; speedup 1.0000x reference)
//
#include <hip/hip_runtime.h>
#include <math.h>

#define NEG_SLOPE 0.2f
#define SH 9            // bin = dst >> SH  (512 dsts per bin)
#define BINW (1 << SH)
#define TILE 4096       // edges per pass-1 tile

static __device__ __forceinline__ float leaky(float x) { return x > 0.f ? x : NEG_SLOPE * x; }

// ---------------- utility ----------------

__global__ void zero_int_kernel(int* __restrict__ p, int n) {
    int i = blockIdx.x * blockDim.x + threadIdx.x;
    if (i < n) p[i] = 0;
}

// ---------------- CSR build (edge_index staged as int32 by harness) ----------------

__global__ __launch_bounds__(256) void histo_bins_kernel(const int* __restrict__ ei_dst, int E,
                                                         int* __restrict__ bin_cnt) {
    __shared__ int hl[256];
    hl[threadIdx.x] = 0;
    __syncthreads();
    int stride = gridDim.x * blockDim.x;
    for (int e = blockIdx.x * blockDim.x + threadIdx.x; e < E; e += stride)
        atomicAdd(&hl[ei_dst[e] >> SH], 1);
    __syncthreads();
    int v = hl[threadIdx.x];
    if (v) atomicAdd(&bin_cnt[threadIdx.x], v);
}

__global__ void scan_bins_kernel(const int* __restrict__ bin_cnt, int nbin,
                                 int* __restrict__ bin_base, int* __restrict__ bin_cur) {
    __shared__ int buf[256];
    int t = threadIdx.x;
    int v = (t < nbin) ? bin_cnt[t] : 0;
    buf[t] = v;
    __syncthreads();
    for (int off = 1; off < 256; off <<= 1) {
        int tv = (t >= off) ? buf[t - off] : 0;
        __syncthreads();
        buf[t] += tv;
        __syncthreads();
    }
    if (t < nbin) {
        int excl = buf[t] - v;
        bin_base[t] = excl;
        bin_cur[t] = excl;
    }
    if (t == nbin - 1) bin_base[nbin] = buf[t];
}

// Pass 1: tile-local sort by bin, coalesced staged writes.
// staged entry: (dst & 511) << 17 | src   (needs N <= 131072)
__global__ __launch_bounds__(256) void bin_sort_kernel(const int* __restrict__ ei, int E, int nbin,
                                                       int* __restrict__ bin_cur,
                                                       unsigned* __restrict__ staged) {
    __shared__ unsigned sorted[TILE];
    __shared__ unsigned char binIdx[TILE];
    __shared__ int hist[256];
    __shared__ int binstart[256];
    __shared__ int goff[256];
    int tid = threadIdx.x;
    int tile0 = blockIdx.x * TILE;
    int cnt = min(TILE, E - tile0);
    hist[tid] = 0;
    __syncthreads();
    unsigned mys[16];
    int myb[16], myo[16];
#pragma unroll
    for (int r = 0; r < 16; r++) {
        int idx = tile0 + tid + r * 256;
        if (idx < E) {
            int s = ei[idx], d = ei[E + idx];
            myb[r] = d >> SH;
            mys[r] = ((unsigned)(d & (BINW - 1)) << 17) | (unsigned)s;
            myo[r] = atomicAdd(&hist[myb[r]], 1);
        } else {
            myb[r] = -1;
        }
    }
    __syncthreads();
    int v = hist[tid];
    binstart[tid] = v;
    __syncthreads();
    for (int off = 1; off < 256; off <<= 1) {
        int t = (tid >= off) ? binstart[tid - off] : 0;
        __syncthreads();
        binstart[tid] += t;
        __syncthreads();
    }
    int incl = binstart[tid];
    __syncthreads();
    binstart[tid] = incl - v;   // exclusive scan
    if (tid < nbin && v > 0) goff[tid] = atomicAdd(&bin_cur[tid], v);
    __syncthreads();
#pragma unroll
    for (int r = 0; r < 16; r++) {
        if (myb[r] >= 0) {
            int lp = binstart[myb[r]] + myo[r];
            sorted[lp] = mys[r];
            binIdx[lp] = (unsigned char)myb[r];
        }
    }
    __syncthreads();
    for (int i = tid; i < cnt; i += 256) {
        int b = binIdx[i];
        staged[goff[b] + (i - binstart[b])] = sorted[i];
    }
}

// Pass 2 (fused): per bin — count per-dst deg, scan, write rowptr, exact scatter. All LDS-local.
__global__ __launch_bounds__(512) void bin_finalize_kernel(const unsigned* __restrict__ staged,
                                                           const int* __restrict__ bin_base,
                                                           int N, int* __restrict__ rowptr,
                                                           int* __restrict__ csr_src) {
    __shared__ int deg[BINW];      // becomes cursor array after scan
    __shared__ int scanbuf[BINW];
    int bin = blockIdx.x, t = threadIdx.x;
    int base = bin << SH;
    int nd = min(BINW, N - base);
    int bs = bin_base[bin], be = bin_base[bin + 1];
    deg[t] = 0;
    __syncthreads();
    for (int i = bs + t; i < be; i += 512) atomicAdd(&deg[staged[i] >> 17], 1);
    __syncthreads();
    int v = (t < nd) ? deg[t] : 0;
    scanbuf[t] = v;
    __syncthreads();
    for (int off = 1; off < BINW; off <<= 1) {
        int tv = (t >= off) ? scanbuf[t - off] : 0;
        __syncthreads();
        scanbuf[t] += tv;
        __syncthreads();
    }
    int excl = bs + scanbuf[t] - v;
    if (t < nd) rowptr[base + t] = excl;
    if (t == 0) rowptr[base + nd] = be;
    __syncthreads();
    if (t < nd) deg[t] = excl;            // cursor
    __syncthreads();
    for (int i = bs + t; i < be; i += 512) {
        unsigned e = staged[i];
        int pos = atomicAdd(&deg[e >> 17], 1);
        csr_src[pos] = (int)(e & 0x1FFFFu);
    }
}

// ---------------- Per-layer: register-tiled GEMM + attention logits ----------------
// Block: 128 rows x 64 cols, BK=64. 256 threads, each computes 8 rows x 4 cols.
// Staging: thread loads float4 slot (tid&15) of row r*16+(tid>>4) — each wave instr
// reads 4 consecutive rows x 256B fully contiguous. Epilogue: LDS-transpose then
// per-lane dword stores (256B contiguous per wave — the pattern measured clean).

template <int K>
__global__ __launch_bounds__(256, 3) void gemm_logits_kernel(
        const float* __restrict__ x, const float* __restrict__ W,
        const float* __restrict__ a_src, const float* __restrict__ a_dst, int n,
        float* __restrict__ h, float* __restrict__ esrc, float* __restrict__ edst) {
    __shared__ float xs[128 * 68];     // stride 68 (pad 4): conflict-free reads
    __shared__ float Wl[64 * 64];
    const int tid = threadIdx.x;
    const int lane = tid & 63;
    const int wv = tid >> 6;
    const int rg = lane >> 4;
    const int cg = lane & 15;
    const int c0 = cg * 4;
    const int row0 = blockIdx.x * 128;
    const int srow = tid >> 4;          // 16 threads per row
    const int sslot = tid & 15;         // float4 slot within 64-float row chunk

    float acc[8][4];
#pragma unroll
    for (int i = 0; i < 8; i++)
#pragma unroll
        for (int j = 0; j < 4; j++) acc[i][j] = 0.f;

#pragma unroll
    for (int k0 = 0; k0 < K; k0 += 64) {
        if (k0) __syncthreads();
        // stage x tile: 128 rows x 64 floats, fully coalesced
#pragma unroll
        for (int r = 0; r < 8; r++) {
            int lr = r * 16 + srow;
            int gr = row0 + lr;
            if (gr >= n) gr = n - 1;
            float4 vv = *reinterpret_cast<const float4*>(&x[(size_t)gr * K + k0 + sslot * 4]);
            *reinterpret_cast<float4*>(&xs[lr * 68 + sslot * 4]) = vv;
        }
        // stage W tile: 64 x 64
#pragma unroll
        for (int j = 0; j < 4; j++) {
            int f = tid + 256 * j;
            int k = f >> 4, c4 = (f & 15) * 4;
            *reinterpret_cast<float4*>(&Wl[k * 64 + c4]) =
                *reinterpret_cast<const float4*>(&W[(size_t)(k0 + k) * 64 + c4]);
        }
        __syncthreads();
#pragma unroll
        for (int k4 = 0; k4 < 16; k4++) {
            float4 w0 = *reinterpret_cast<const float4*>(&Wl[(k4 * 4 + 0) * 64 + c0]);
            float4 w1 = *reinterpret_cast<const float4*>(&Wl[(k4 * 4 + 1) * 64 + c0]);
            float4 w2 = *reinterpret_cast<const float4*>(&Wl[(k4 * 4 + 2) * 64 + c0]);
            float4 w3 = *reinterpret_cast<const float4*>(&Wl[(k4 * 4 + 3) * 64 + c0]);
#pragma unroll
            for (int i = 0; i < 8; i++) {
                int lr = wv * 32 + i * 4 + rg;
                float4 xv = *reinterpret_cast<const float4*>(&xs[lr * 68 + k4 * 4]);
                acc[i][0] += xv.x * w0.x + xv.y * w1.x + xv.z * w2.x + xv.w * w3.x;
                acc[i][1] += xv.x * w0.y + xv.y * w1.y + xv.z * w2.y + xv.w * w3.y;
                acc[i][2] += xv.x * w0.z + xv.y * w1.z + xv.z * w2.z + xv.w * w3.z;
                acc[i][3] += xv.x * w0.w + xv.y * w1.w + xv.z * w2.w + xv.w * w3.w;
            }
        }
    }

    // attention logits from accumulators (reduce across cg lanes)
    float as4[4], ad4[4];
#pragma unroll
    for (int j = 0; j < 4; j++) { as4[j] = a_src[c0 + j]; ad4[j] = a_dst[c0 + j]; }
#pragma unroll
    for (int i = 0; i < 8; i++) {
        int r = row0 + wv * 32 + i * 4 + rg;
        float ps = acc[i][0] * as4[0] + acc[i][1] * as4[1] + acc[i][2] * as4[2] + acc[i][3] * as4[3];
        float pd = acc[i][0] * ad4[0] + acc[i][1] * ad4[1] + acc[i][2] * ad4[2] + acc[i][3] * ad4[3];
        ps += __shfl_xor(ps, 1); ps += __shfl_xor(ps, 2); ps += __shfl_xor(ps, 4); ps += __shfl_xor(ps, 8);
        pd += __shfl_xor(pd, 1); pd += __shfl_xor(pd, 2); pd += __shfl_xor(pd, 4); pd += __shfl_xor(pd, 8);
        if (cg == 0 && r < n) { esrc[r] = ps; edst[r] = pd; }
    }

    // h store: transpose through LDS, then per-lane dword stores (contiguous 256B/wave)
    __syncthreads();
#pragma unroll
    for (int i = 0; i < 8; i++) {
        int lr = wv * 32 + i * 4 + rg;
        *reinterpret_cast<float4*>(&xs[lr * 68 + c0]) =
            make_float4(acc[i][0], acc[i][1], acc[i][2], acc[i][3]);
    }
    __syncthreads();
#pragma unroll
    for (int p = 0; p < 32; p++) {
        int idx = p * 256 + tid;
        int row = idx >> 6, col = idx & 63;
        int gr = row0 + row;
        if (gr < n) h[(size_t)gr * 64 + col] = xs[row * 68 + col];
    }
}

// ---------------- Per-layer: softmax + aggregate (one wave per dst) ----------------

#define GATHER8(J)                                                                  \
    {                                                                               \
        float w0 = __shfl(w, (J) + 0), w1 = __shfl(w, (J) + 1);                     \
        float w2 = __shfl(w, (J) + 2), w3 = __shfl(w, (J) + 3);                     \
        float w4_ = __shfl(w, (J) + 4), w5 = __shfl(w, (J) + 5);                    \
        float w6 = __shfl(w, (J) + 6), w7 = __shfl(w, (J) + 7);                     \
        int s0 = __shfl(sN, (J) + 0), s1 = __shfl(sN, (J) + 1);                     \
        int s2 = __shfl(sN, (J) + 2), s3 = __shfl(sN, (J) + 3);                     \
        int s4 = __shfl(sN, (J) + 4), s5 = __shfl(sN, (J) + 5);                     \
        int s6 = __shfl(sN, (J) + 6), s7 = __shfl(sN, (J) + 7);                     \
        float g0 = h[(size_t)s0 * 64 + lane], g1 = h[(size_t)s1 * 64 + lane];       \
        float g2 = h[(size_t)s2 * 64 + lane], g3 = h[(size_t)s3 * 64 + lane];       \
        float g4 = h[(size_t)s4 * 64 + lane], g5 = h[(size_t)s5 * 64 + lane];       \
        float g6 = h[(size_t)s6 * 64 + lane], g7 = h[(size_t)s7 * 64 + lane];       \
        acc += w0 * g0; acc += w1 * g1; acc += w2 * g2; acc += w3 * g3;             \
        acc += w4_ * g4; acc += w5 * g5; acc += w6 * g6; acc += w7 * g7;            \
    }

__global__ __launch_bounds__(256) void gat_aggregate_kernel(
        const float* __restrict__ h, const float* __restrict__ esrc, const float* __restrict__ edst,
        const int* __restrict__ rowptr, const int* __restrict__ csr_src,
        const float* __restrict__ bias, int n, int do_relu, float* __restrict__ out) {
    int wave = threadIdx.x >> 6, lane = threadIdx.x & 63;
    for (int dst = blockIdx.x * 4 + wave; dst < n; dst += gridDim.x * 4) {
        int rs = rowptr[dst], re = rowptr[dst + 1];
        int deg = re - rs;
        float ed = edst[dst];
        float eself = leaky(esrc[dst] + ed);
        float acc;
        if (deg <= 64) {
            int i = rs + lane;
            bool valid = i < re;
            int sN = valid ? csr_src[i] : 0;
            float e = valid ? leaky(esrc[sN] + ed) : -1e30f;
            float m = fmaxf(e, eself);
#pragma unroll
            for (int off = 32; off; off >>= 1) m = fmaxf(m, __shfl_xor(m, off));
            float p = valid ? expf(e - m) : 0.f;
            float s = p;
#pragma unroll
            for (int off = 32; off; off >>= 1) s += __shfl_xor(s, off);
            float pself = expf(eself - m);
            s += pself;
            float inv_s = 1.f / s;
            acc = pself * inv_s * h[(size_t)dst * 64 + lane];
            float w = p * inv_s;
            int j = 0;
            for (; j + 8 <= deg; j += 8) GATHER8(j);
            for (; j < deg; j++) {
                float wj = __shfl(w, j);
                int sj = __shfl(sN, j);
                acc += wj * h[(size_t)sj * 64 + lane];
            }
        } else {
            float m = eself, s = (lane == 0) ? 1.f : 0.f;
            for (int i = rs + lane; i < re; i += 64) {
                int sN = csr_src[i];
                float e = leaky(esrc[sN] + ed);
                float nm = fmaxf(m, e);
                s = s * expf(m - nm) + expf(e - nm);
                m = nm;
            }
#pragma unroll
            for (int off = 32; off; off >>= 1) {
                float m2 = __shfl_xor(m, off), s2 = __shfl_xor(s, off);
                float nm = fmaxf(m, m2);
                s = s * expf(m - nm) + s2 * expf(m2 - nm);
                m = nm;
            }
            float inv_s = 1.f / s;
            acc = expf(eself - m) * inv_s * h[(size_t)dst * 64 + lane];
            for (int base = rs; base < re; base += 64) {
                int i = base + lane;
                int sN = 0;
                float w = 0.f;
                if (i < re) {
                    sN = csr_src[i];
                    w = expf(leaky(esrc[sN] + ed) - m) * inv_s;
                }
                int cnt = min(64, re - base);
                int j = 0;
                for (; j + 8 <= cnt; j += 8) GATHER8(j);
                for (; j < cnt; j++) {
                    float wj = __shfl(w, j);
                    int sj = __shfl(sN, j);
                    acc += wj * h[(size_t)sj * 64 + lane];
                }
            }
        }
        float v = acc + bias[lane];
        if (do_relu) v = fmaxf(v, 0.f);
        out[(size_t)dst * 64 + lane] = v;
    }
}

// ---------------- launch ----------------

extern "C" void kernel_launch(void* const* d_in, const int* in_sizes, int n_in,
                              void* d_out, int out_size, void* d_ws, size_t ws_size,
                              hipStream_t stream) {
    const float* x = (const float*)d_in[0];
    const int* ei = (const int*)d_in[1];   // harness stages integer inputs as int32
    const float* W1 = (const float*)d_in[2];
    const float* as1 = (const float*)d_in[3];
    const float* ad1 = (const float*)d_in[4];
    const float* b1 = (const float*)d_in[5];
    const float* W2 = (const float*)d_in[6];
    const float* as2 = (const float*)d_in[7];
    const float* ad2 = (const float*)d_in[8];
    const float* b2 = (const float*)d_in[9];
    const float* W3 = (const float*)d_in[10];
    const float* as3 = (const float*)d_in[11];
    const float* ad3 = (const float*)d_in[12];
    const float* b3 = (const float*)d_in[13];

    const int FIN = 128, HID = 64;
    int N = in_sizes[0] / FIN;
    int E = in_sizes[1] / 2;
    int nbin = (N + BINW - 1) >> SH;          // 196 for N=100k (must be <= 256)

    char* base = (char*)d_ws;
    size_t off = 0;
    auto alloc = [&](size_t bytes) -> void* {
        void* p = base + off;
        off = (off + bytes + 255) & ~(size_t)255;
        return p;
    };
    int* rowptr = (int*)alloc((size_t)(N + 1) * 4);
    int* bin_cnt = (int*)alloc((size_t)nbin * 4);
    int* bin_base = (int*)alloc((size_t)(nbin + 1) * 4);
    int* bin_cur = (int*)alloc((size_t)nbin * 4);
    int* csr_src = (int*)alloc((size_t)E * 4);
    float* esrc = (float*)alloc((size_t)N * 4);
    float* edst = (float*)alloc((size_t)N * 4);
    float* hA = (float*)alloc((size_t)N * HID * 4);
    unsigned* staged = (unsigned*)hA;   // alias: staging is dead before first gemm writes hA
    (void)ws_size;
    (void)n_in;

    float* out = (float*)d_out;   // doubles as the ping buffer between layers

    // ---- CSR build (graph identical across the 3 layers; no per-dst global atomics) ----
    zero_int_kernel<<<1, 256, 0, stream>>>(bin_cnt, nbin);
    histo_bins_kernel<<<2048, 256, 0, stream>>>(ei + E, E, bin_cnt);
    scan_bins_kernel<<<1, 256, 0, stream>>>(bin_cnt, nbin, bin_base, bin_cur);
    bin_sort_kernel<<<(E + TILE - 1) / TILE, 256, 0, stream>>>(ei, E, nbin, bin_cur, staged);
    bin_finalize_kernel<<<nbin, 512, 0, stream>>>(staged, bin_base, N, rowptr, csr_src);

    int agrid = (N + 3) / 4;
    int ggrid = (N + 127) / 128;

    // layer 1: x -> hA -> out (relu)
    gemm_logits_kernel<128><<<ggrid, 256, 0, stream>>>(x, W1, as1, ad1, N, hA, esrc, edst);
    gat_aggregate_kernel<<<agrid, 256, 0, stream>>>(hA, esrc, edst, rowptr, csr_src, b1, N, 1, out);
    // layer 2: out -> hA -> out (relu)
    gemm_logits_kernel<64><<<ggrid, 256, 0, stream>>>(out, W2, as2, ad2, N, hA, esrc, edst);
    gat_aggregate_kernel<<<agrid, 256, 0, stream>>>(hA, esrc, edst, rowptr, csr_src, b2, N, 1, out);
    // layer 3: out -> hA -> out (no relu)
    gemm_logits_kernel<64><<<ggrid, 256, 0, stream>>>(out, W3, as3, ad3, N, hA, esrc, edst);
    gat_aggregate_kernel<<<agrid, 256, 0, stream>>>(hA, esrc, edst, rowptr, csr_src, b3, N, 0, out);
}

// Round 6
// 821.095 us; speedup vs baseline: 3.3365x; 3.3365x over previous
//
#include <hip/hip_runtime.h>
#include <math.h>

#define NEG_SLOPE 0.2f
#define SH 9            // bin = dst >> SH  (512 dsts per bin)
#define BINW (1 << SH)
#define TILE 4096       // edges per pass-1 tile

static __device__ __forceinline__ float leaky(float x) { return x > 0.f ? x : NEG_SLOPE * x; }

// ---------------- utility ----------------

__global__ void zero_int_kernel(int* __restrict__ p, int n) {
    int i = blockIdx.x * blockDim.x + threadIdx.x;
    if (i < n) p[i] = 0;
}

// ---------------- CSR build (edge_index staged as int32 by harness) ----------------

__global__ __launch_bounds__(256) void histo_bins_kernel(const int* __restrict__ ei_dst, int E,
                                                         int* __restrict__ bin_cnt) {
    __shared__ int hl[256];
    hl[threadIdx.x] = 0;
    __syncthreads();
    int stride = gridDim.x * blockDim.x;
    for (int e = blockIdx.x * blockDim.x + threadIdx.x; e < E; e += stride)
        atomicAdd(&hl[ei_dst[e] >> SH], 1);
    __syncthreads();
    int v = hl[threadIdx.x];
    if (v) atomicAdd(&bin_cnt[threadIdx.x], v);
}

__global__ void scan_bins_kernel(const int* __restrict__ bin_cnt, int nbin,
                                 int* __restrict__ bin_base, int* __restrict__ bin_cur) {
    __shared__ int buf[256];
    int t = threadIdx.x;
    int v = (t < nbin) ? bin_cnt[t] : 0;
    buf[t] = v;
    __syncthreads();
    for (int off = 1; off < 256; off <<= 1) {
        int tv = (t >= off) ? buf[t - off] : 0;
        __syncthreads();
        buf[t] += tv;
        __syncthreads();
    }
    if (t < nbin) {
        int excl = buf[t] - v;
        bin_base[t] = excl;
        bin_cur[t] = excl;
    }
    if (t == nbin - 1) bin_base[nbin] = buf[t];
}

// Pass 1: tile-local sort by bin, coalesced staged writes.
// staged entry: (dst & 511) << 17 | src   (needs N <= 131072)
__global__ __launch_bounds__(256) void bin_sort_kernel(const int* __restrict__ ei, int E, int nbin,
                                                       int* __restrict__ bin_cur,
                                                       unsigned* __restrict__ staged) {
    __shared__ unsigned sorted[TILE];
    __shared__ unsigned char binIdx[TILE];
    __shared__ int hist[256];
    __shared__ int binstart[256];
    __shared__ int goff[256];
    int tid = threadIdx.x;
    int tile0 = blockIdx.x * TILE;
    int cnt = min(TILE, E - tile0);
    hist[tid] = 0;
    __syncthreads();
    unsigned mys[16];
    int myb[16], myo[16];
#pragma unroll
    for (int r = 0; r < 16; r++) {
        int idx = tile0 + tid + r * 256;
        if (idx < E) {
            int s = ei[idx], d = ei[E + idx];
            myb[r] = d >> SH;
            mys[r] = ((unsigned)(d & (BINW - 1)) << 17) | (unsigned)s;
            myo[r] = atomicAdd(&hist[myb[r]], 1);
        } else {
            myb[r] = -1;
        }
    }
    __syncthreads();
    int v = hist[tid];
    binstart[tid] = v;
    __syncthreads();
    for (int off = 1; off < 256; off <<= 1) {
        int t = (tid >= off) ? binstart[tid - off] : 0;
        __syncthreads();
        binstart[tid] += t;
        __syncthreads();
    }
    int incl = binstart[tid];
    __syncthreads();
    binstart[tid] = incl - v;   // exclusive scan
    if (tid < nbin && v > 0) goff[tid] = atomicAdd(&bin_cur[tid], v);
    __syncthreads();
#pragma unroll
    for (int r = 0; r < 16; r++) {
        if (myb[r] >= 0) {
            int lp = binstart[myb[r]] + myo[r];
            sorted[lp] = mys[r];
            binIdx[lp] = (unsigned char)myb[r];
        }
    }
    __syncthreads();
    for (int i = tid; i < cnt; i += 256) {
        int b = binIdx[i];
        staged[goff[b] + (i - binstart[b])] = sorted[i];
    }
}

// Pass 2 (fused): per bin — count per-dst deg, scan, write rowptr, exact scatter. All LDS-local.
__global__ __launch_bounds__(512) void bin_finalize_kernel(const unsigned* __restrict__ staged,
                                                           const int* __restrict__ bin_base,
                                                           int N, int* __restrict__ rowptr,
                                                           int* __restrict__ csr_src) {
    __shared__ int deg[BINW];      // becomes cursor array after scan
    __shared__ int scanbuf[BINW];
    int bin = blockIdx.x, t = threadIdx.x;
    int base = bin << SH;
    int nd = min(BINW, N - base);
    int bs = bin_base[bin], be = bin_base[bin + 1];
    deg[t] = 0;
    __syncthreads();
    for (int i = bs + t; i < be; i += 512) atomicAdd(&deg[staged[i] >> 17], 1);
    __syncthreads();
    int v = (t < nd) ? deg[t] : 0;
    scanbuf[t] = v;
    __syncthreads();
    for (int off = 1; off < BINW; off <<= 1) {
        int tv = (t >= off) ? scanbuf[t - off] : 0;
        __syncthreads();
        scanbuf[t] += tv;
        __syncthreads();
    }
    int excl = bs + scanbuf[t] - v;
    if (t < nd) rowptr[base + t] = excl;
    if (t == 0) rowptr[base + nd] = be;
    __syncthreads();
    if (t < nd) deg[t] = excl;            // cursor
    __syncthreads();
    for (int i = bs + t; i < be; i += 512) {
        unsigned e = staged[i];
        int pos = atomicAdd(&deg[e >> 17], 1);
        csr_src[pos] = (int)(e & 0x1FFFFu);
    }
}

// ---------------- Per-layer: GEMM + attention logits ----------------
// W column `lane` lives in registers (64 cols == 64 lanes). Inner loop: 4 rows in
// flight, wave-uniform float4 x loads (measured clean in round 3), register-only
// FMAs (no LDS on the critical path). Epilogue: per-lane dword h stores (wave =
// 256B contiguous, the measured-clean pattern) + butterfly-reduced logits.

template <int K>
__global__ __launch_bounds__(256) void gemm_logits_kernel(
        const float* __restrict__ x, const float* __restrict__ W,
        const float* __restrict__ a_src, const float* __restrict__ a_dst, int n,
        float* __restrict__ h, float* __restrict__ esrc, float* __restrict__ edst) {
    const int lane = threadIdx.x & 63;
    float wr[K];
#pragma unroll
    for (int k = 0; k < K; k++) wr[k] = W[k * 64 + lane];
    const float asl = a_src[lane], adl = a_dst[lane];

    const int wid = (blockIdx.x << 2) + (threadIdx.x >> 6);
    const int wstride = gridDim.x << 2;
    for (int g = wid; (g << 2) < n; g += wstride) {
        const int r0 = g << 2;
        const int r1 = min(r0 + 1, n - 1);
        const int r2 = min(r0 + 2, n - 1);
        const int r3 = min(r0 + 3, n - 1);
        const float4* p0 = reinterpret_cast<const float4*>(x + (size_t)r0 * K);
        const float4* p1 = reinterpret_cast<const float4*>(x + (size_t)r1 * K);
        const float4* p2 = reinterpret_cast<const float4*>(x + (size_t)r2 * K);
        const float4* p3 = reinterpret_cast<const float4*>(x + (size_t)r3 * K);
        float a0 = 0.f, a1 = 0.f, a2 = 0.f, a3 = 0.f;
#pragma unroll
        for (int q = 0; q < K / 4; q++) {
            float4 f0 = p0[q], f1 = p1[q], f2 = p2[q], f3 = p3[q];
            a0 += f0.x * wr[4 * q + 0] + f0.y * wr[4 * q + 1] + f0.z * wr[4 * q + 2] + f0.w * wr[4 * q + 3];
            a1 += f1.x * wr[4 * q + 0] + f1.y * wr[4 * q + 1] + f1.z * wr[4 * q + 2] + f1.w * wr[4 * q + 3];
            a2 += f2.x * wr[4 * q + 0] + f2.y * wr[4 * q + 1] + f2.z * wr[4 * q + 2] + f2.w * wr[4 * q + 3];
            a3 += f3.x * wr[4 * q + 0] + f3.y * wr[4 * q + 1] + f3.z * wr[4 * q + 2] + f3.w * wr[4 * q + 3];
        }
        // attention logits (full-wave butterfly; result valid in all lanes)
        float s0 = a0 * asl, d0 = a0 * adl;
        float s1 = a1 * asl, d1 = a1 * adl;
        float s2 = a2 * asl, d2 = a2 * adl;
        float s3 = a3 * asl, d3 = a3 * adl;
#pragma unroll
        for (int o = 32; o; o >>= 1) {
            s0 += __shfl_xor(s0, o); d0 += __shfl_xor(d0, o);
            s1 += __shfl_xor(s1, o); d1 += __shfl_xor(d1, o);
            s2 += __shfl_xor(s2, o); d2 += __shfl_xor(d2, o);
            s3 += __shfl_xor(s3, o); d3 += __shfl_xor(d3, o);
        }
        // stores: wave writes 4 x 256B contiguous rows
        h[(size_t)r0 * 64 + lane] = a0;
        if (r0 + 1 < n) h[(size_t)r1 * 64 + lane] = a1;
        if (r0 + 2 < n) h[(size_t)r2 * 64 + lane] = a2;
        if (r0 + 3 < n) h[(size_t)r3 * 64 + lane] = a3;
        if (lane == 0) {
            esrc[r0] = s0; edst[r0] = d0;
            if (r0 + 1 < n) { esrc[r1] = s1; edst[r1] = d1; }
            if (r0 + 2 < n) { esrc[r2] = s2; edst[r2] = d2; }
            if (r0 + 3 < n) { esrc[r3] = s3; edst[r3] = d3; }
        }
    }
}

// ---------------- Per-layer: softmax + aggregate (one wave per dst) ----------------

#define GATHER8(J)                                                                  \
    {                                                                               \
        float w0 = __shfl(w, (J) + 0), w1 = __shfl(w, (J) + 1);                     \
        float w2 = __shfl(w, (J) + 2), w3 = __shfl(w, (J) + 3);                     \
        float w4_ = __shfl(w, (J) + 4), w5 = __shfl(w, (J) + 5);                    \
        float w6 = __shfl(w, (J) + 6), w7 = __shfl(w, (J) + 7);                     \
        int s0 = __shfl(sN, (J) + 0), s1 = __shfl(sN, (J) + 1);                     \
        int s2 = __shfl(sN, (J) + 2), s3 = __shfl(sN, (J) + 3);                     \
        int s4 = __shfl(sN, (J) + 4), s5 = __shfl(sN, (J) + 5);                     \
        int s6 = __shfl(sN, (J) + 6), s7 = __shfl(sN, (J) + 7);                     \
        float g0 = h[(size_t)s0 * 64 + lane], g1 = h[(size_t)s1 * 64 + lane];       \
        float g2 = h[(size_t)s2 * 64 + lane], g3 = h[(size_t)s3 * 64 + lane];       \
        float g4 = h[(size_t)s4 * 64 + lane], g5 = h[(size_t)s5 * 64 + lane];       \
        float g6 = h[(size_t)s6 * 64 + lane], g7 = h[(size_t)s7 * 64 + lane];       \
        acc += w0 * g0; acc += w1 * g1; acc += w2 * g2; acc += w3 * g3;             \
        acc += w4_ * g4; acc += w5 * g5; acc += w6 * g6; acc += w7 * g7;            \
    }

__global__ __launch_bounds__(256) void gat_aggregate_kernel(
        const float* __restrict__ h, const float* __restrict__ esrc, const float* __restrict__ edst,
        const int* __restrict__ rowptr, const int* __restrict__ csr_src,
        const float* __restrict__ bias, int n, int do_relu, float* __restrict__ out) {
    int wave = threadIdx.x >> 6, lane = threadIdx.x & 63;
    for (int dst = blockIdx.x * 4 + wave; dst < n; dst += gridDim.x * 4) {
        int rs = rowptr[dst], re = rowptr[dst + 1];
        int deg = re - rs;
        float ed = edst[dst];
        float eself = leaky(esrc[dst] + ed);
        float acc;
        if (deg <= 64) {
            int i = rs + lane;
            bool valid = i < re;
            int sN = valid ? csr_src[i] : 0;
            float e = valid ? leaky(esrc[sN] + ed) : -1e30f;
            float m = fmaxf(e, eself);
#pragma unroll
            for (int off = 32; off; off >>= 1) m = fmaxf(m, __shfl_xor(m, off));
            float p = valid ? expf(e - m) : 0.f;
            float s = p;
#pragma unroll
            for (int off = 32; off; off >>= 1) s += __shfl_xor(s, off);
            float pself = expf(eself - m);
            s += pself;
            float inv_s = 1.f / s;
            acc = pself * inv_s * h[(size_t)dst * 64 + lane];
            float w = p * inv_s;
            int j = 0;
            for (; j + 8 <= deg; j += 8) GATHER8(j);
            for (; j < deg; j++) {
                float wj = __shfl(w, j);
                int sj = __shfl(sN, j);
                acc += wj * h[(size_t)sj * 64 + lane];
            }
        } else {
            float m = eself, s = (lane == 0) ? 1.f : 0.f;
            for (int i = rs + lane; i < re; i += 64) {
                int sN = csr_src[i];
                float e = leaky(esrc[sN] + ed);
                float nm = fmaxf(m, e);
                s = s * expf(m - nm) + expf(e - nm);
                m = nm;
            }
#pragma unroll
            for (int off = 32; off; off >>= 1) {
                float m2 = __shfl_xor(m, off), s2 = __shfl_xor(s, off);
                float nm = fmaxf(m, m2);
                s = s * expf(m - nm) + s2 * expf(m2 - nm);
                m = nm;
            }
            float inv_s = 1.f / s;
            acc = expf(eself - m) * inv_s * h[(size_t)dst * 64 + lane];
            for (int base = rs; base < re; base += 64) {
                int i = base + lane;
                int sN = 0;
                float w = 0.f;
                if (i < re) {
                    sN = csr_src[i];
                    w = expf(leaky(esrc[sN] + ed) - m) * inv_s;
                }
                int cnt = min(64, re - base);
                int j = 0;
                for (; j + 8 <= cnt; j += 8) GATHER8(j);
                for (; j < cnt; j++) {
                    float wj = __shfl(w, j);
                    int sj = __shfl(sN, j);
                    acc += wj * h[(size_t)sj * 64 + lane];
                }
            }
        }
        float v = acc + bias[lane];
        if (do_relu) v = fmaxf(v, 0.f);
        out[(size_t)dst * 64 + lane] = v;
    }
}

// ---------------- launch ----------------

extern "C" void kernel_launch(void* const* d_in, const int* in_sizes, int n_in,
                              void* d_out, int out_size, void* d_ws, size_t ws_size,
                              hipStream_t stream) {
    const float* x = (const float*)d_in[0];
    const int* ei = (const int*)d_in[1];   // harness stages integer inputs as int32
    const float* W1 = (const float*)d_in[2];
    const float* as1 = (const float*)d_in[3];
    const float* ad1 = (const float*)d_in[4];
    const float* b1 = (const float*)d_in[5];
    const float* W2 = (const float*)d_in[6];
    const float* as2 = (const float*)d_in[7];
    const float* ad2 = (const float*)d_in[8];
    const float* b2 = (const float*)d_in[9];
    const float* W3 = (const float*)d_in[10];
    const float* as3 = (const float*)d_in[11];
    const float* ad3 = (const float*)d_in[12];
    const float* b3 = (const float*)d_in[13];

    const int FIN = 128, HID = 64;
    int N = in_sizes[0] / FIN;
    int E = in_sizes[1] / 2;
    int nbin = (N + BINW - 1) >> SH;          // 196 for N=100k (must be <= 256)

    char* base = (char*)d_ws;
    size_t off = 0;
    auto alloc = [&](size_t bytes) -> void* {
        void* p = base + off;
        off = (off + bytes + 255) & ~(size_t)255;
        return p;
    };
    int* rowptr = (int*)alloc((size_t)(N + 1) * 4);
    int* bin_cnt = (int*)alloc((size_t)nbin * 4);
    int* bin_base = (int*)alloc((size_t)(nbin + 1) * 4);
    int* bin_cur = (int*)alloc((size_t)nbin * 4);
    int* csr_src = (int*)alloc((size_t)E * 4);
    float* esrc = (float*)alloc((size_t)N * 4);
    float* edst = (float*)alloc((size_t)N * 4);
    float* hA = (float*)alloc((size_t)N * HID * 4);
    unsigned* staged = (unsigned*)hA;   // alias: staging is dead before first gemm writes hA
    (void)ws_size;
    (void)n_in;

    float* out = (float*)d_out;   // doubles as the ping buffer between layers

    // ---- CSR build (graph identical across the 3 layers; no per-dst global atomics) ----
    zero_int_kernel<<<1, 256, 0, stream>>>(bin_cnt, nbin);
    histo_bins_kernel<<<2048, 256, 0, stream>>>(ei + E, E, bin_cnt);
    scan_bins_kernel<<<1, 256, 0, stream>>>(bin_cnt, nbin, bin_base, bin_cur);
    bin_sort_kernel<<<(E + TILE - 1) / TILE, 256, 0, stream>>>(ei, E, nbin, bin_cur, staged);
    bin_finalize_kernel<<<nbin, 512, 0, stream>>>(staged, bin_base, N, rowptr, csr_src);

    int agrid = (N + 3) / 4;
    int ggrid = 2048;   // grid-stride: ~12 row-groups per wave amortize the W register load

    // layer 1: x -> hA -> out (relu)
    gemm_logits_kernel<128><<<ggrid, 256, 0, stream>>>(x, W1, as1, ad1, N, hA, esrc, edst);
    gat_aggregate_kernel<<<agrid, 256, 0, stream>>>(hA, esrc, edst, rowptr, csr_src, b1, N, 1, out);
    // layer 2: out -> hA -> out (relu)
    gemm_logits_kernel<64><<<ggrid, 256, 0, stream>>>(out, W2, as2, ad2, N, hA, esrc, edst);
    gat_aggregate_kernel<<<agrid, 256, 0, stream>>>(hA, esrc, edst, rowptr, csr_src, b2, N, 1, out);
    // layer 3: out -> hA -> out (no relu)
    gemm_logits_kernel<64><<<ggrid, 256, 0, stream>>>(out, W3, as3, ad3, N, hA, esrc, edst);
    gat_aggregate_kernel<<<agrid, 256, 0, stream>>>(hA, esrc, edst, rowptr, csr_src, b3, N, 0, out);
}

// Round 7
// 675.103 us; speedup vs baseline: 4.0580x; 1.2163x over previous
//
#include <hip/hip_runtime.h>
#include <math.h>

#define NEG_SLOPE 0.2f
#define SH 9            // bin = dst >> SH  (512 dsts per bin)
#define BINW (1 << SH)
#define TILE 4096       // edges per pass-1 tile

static __device__ __forceinline__ float leaky(float x) { return x > 0.f ? x : NEG_SLOPE * x; }

// ---------------- utility ----------------

__global__ void zero_int_kernel(int* __restrict__ p, int n) {
    int i = blockIdx.x * blockDim.x + threadIdx.x;
    if (i < n) p[i] = 0;
}

// ---------------- CSR build (edge_index staged as int32 by harness) ----------------

__global__ __launch_bounds__(256) void histo_bins_kernel(const int* __restrict__ ei_dst, int E,
                                                         int* __restrict__ bin_cnt) {
    __shared__ int hl[256];
    hl[threadIdx.x] = 0;
    __syncthreads();
    int stride = gridDim.x * blockDim.x;
    for (int e = blockIdx.x * blockDim.x + threadIdx.x; e < E; e += stride)
        atomicAdd(&hl[ei_dst[e] >> SH], 1);
    __syncthreads();
    int v = hl[threadIdx.x];
    if (v) atomicAdd(&bin_cnt[threadIdx.x], v);
}

__global__ void scan_bins_kernel(const int* __restrict__ bin_cnt, int nbin,
                                 int* __restrict__ bin_base, int* __restrict__ bin_cur) {
    __shared__ int buf[256];
    int t = threadIdx.x;
    int v = (t < nbin) ? bin_cnt[t] : 0;
    buf[t] = v;
    __syncthreads();
    for (int off = 1; off < 256; off <<= 1) {
        int tv = (t >= off) ? buf[t - off] : 0;
        __syncthreads();
        buf[t] += tv;
        __syncthreads();
    }
    if (t < nbin) {
        int excl = buf[t] - v;
        bin_base[t] = excl;
        bin_cur[t] = excl;
    }
    if (t == nbin - 1) bin_base[nbin] = buf[t];
}

// Pass 1: tile-local sort by bin, coalesced staged writes.
// staged entry: (dst & 511) << 17 | src   (needs N <= 131072)
__global__ __launch_bounds__(256) void bin_sort_kernel(const int* __restrict__ ei, int E, int nbin,
                                                       int* __restrict__ bin_cur,
                                                       unsigned* __restrict__ staged) {
    __shared__ unsigned sorted[TILE];
    __shared__ unsigned char binIdx[TILE];
    __shared__ int hist[256];
    __shared__ int binstart[256];
    __shared__ int goff[256];
    int tid = threadIdx.x;
    int tile0 = blockIdx.x * TILE;
    int cnt = min(TILE, E - tile0);
    hist[tid] = 0;
    __syncthreads();
    unsigned mys[16];
    int myb[16], myo[16];
#pragma unroll
    for (int r = 0; r < 16; r++) {
        int idx = tile0 + tid + r * 256;
        if (idx < E) {
            int s = ei[idx], d = ei[E + idx];
            myb[r] = d >> SH;
            mys[r] = ((unsigned)(d & (BINW - 1)) << 17) | (unsigned)s;
            myo[r] = atomicAdd(&hist[myb[r]], 1);
        } else {
            myb[r] = -1;
        }
    }
    __syncthreads();
    int v = hist[tid];
    binstart[tid] = v;
    __syncthreads();
    for (int off = 1; off < 256; off <<= 1) {
        int t = (tid >= off) ? binstart[tid - off] : 0;
        __syncthreads();
        binstart[tid] += t;
        __syncthreads();
    }
    int incl = binstart[tid];
    __syncthreads();
    binstart[tid] = incl - v;   // exclusive scan
    if (tid < nbin && v > 0) goff[tid] = atomicAdd(&bin_cur[tid], v);
    __syncthreads();
#pragma unroll
    for (int r = 0; r < 16; r++) {
        if (myb[r] >= 0) {
            int lp = binstart[myb[r]] + myo[r];
            sorted[lp] = mys[r];
            binIdx[lp] = (unsigned char)myb[r];
        }
    }
    __syncthreads();
    for (int i = tid; i < cnt; i += 256) {
        int b = binIdx[i];
        staged[goff[b] + (i - binstart[b])] = sorted[i];
    }
}

// Pass 2 (fused): per bin — count per-dst deg, scan, write rowptr, exact scatter. All LDS-local.
__global__ __launch_bounds__(512) void bin_finalize_kernel(const unsigned* __restrict__ staged,
                                                           const int* __restrict__ bin_base,
                                                           int N, int* __restrict__ rowptr,
                                                           int* __restrict__ csr_src) {
    __shared__ int deg[BINW];      // becomes cursor array after scan
    __shared__ int scanbuf[BINW];
    int bin = blockIdx.x, t = threadIdx.x;
    int base = bin << SH;
    int nd = min(BINW, N - base);
    int bs = bin_base[bin], be = bin_base[bin + 1];
    deg[t] = 0;
    __syncthreads();
    for (int i = bs + t; i < be; i += 512) atomicAdd(&deg[staged[i] >> 17], 1);
    __syncthreads();
    int v = (t < nd) ? deg[t] : 0;
    scanbuf[t] = v;
    __syncthreads();
    for (int off = 1; off < BINW; off <<= 1) {
        int tv = (t >= off) ? scanbuf[t - off] : 0;
        __syncthreads();
        scanbuf[t] += tv;
        __syncthreads();
    }
    int excl = bs + scanbuf[t] - v;
    if (t < nd) rowptr[base + t] = excl;
    if (t == 0) rowptr[base + nd] = be;
    __syncthreads();
    if (t < nd) deg[t] = excl;            // cursor
    __syncthreads();
    for (int i = bs + t; i < be; i += 512) {
        unsigned e = staged[i];
        int pos = atomicAdd(&deg[e >> 17], 1);
        csr_src[pos] = (int)(e & 0x1FFFFu);
    }
}

// ---------------- Per-layer: GEMM + attention logits ----------------
// W column `lane` in registers; x-tile (64 rows) staged to LDS with per-lane
// contiguous float4 loads (1KB/instr); inner loop reads x via uniform-address
// LDS float4 (broadcast, conflict-free) + register-only FMAs. Epilogue: per-lane
// dword h stores (wave = 256B contiguous) + butterfly-reduced logits.

template <int K>
__global__ __launch_bounds__(256) void gemm_logits_kernel(
        const float* __restrict__ x, const float* __restrict__ W,
        const float* __restrict__ a_src, const float* __restrict__ a_dst, int n,
        float* __restrict__ h, float* __restrict__ esrc, float* __restrict__ edst) {
    __shared__ float xs[64 * K];
    const int tid = threadIdx.x;
    const int lane = tid & 63;
    const int wv = tid >> 6;

    float wr[K];
#pragma unroll
    for (int k = 0; k < K; k++) wr[k] = W[k * 64 + lane];
    const float asl = a_src[lane], adl = a_dst[lane];

    const int row0 = blockIdx.x * 64;

    // stage 64-row x tile, fully coalesced float4 loads
    constexpr int F4_PER_ROW = K / 4;            // 16 (K=64) or 32 (K=128)
    constexpr int NP = 64 * F4_PER_ROW / 256;    // 4 or 8 per thread
#pragma unroll
    for (int p = 0; p < NP; p++) {
        int f = p * 256 + tid;
        int row = f / F4_PER_ROW;
        int slot = f % F4_PER_ROW;
        int gr = row0 + row;
        if (gr >= n) gr = n - 1;
        *reinterpret_cast<float4*>(&xs[row * K + slot * 4]) =
            *reinterpret_cast<const float4*>(&x[(size_t)gr * K + slot * 4]);
    }
    __syncthreads();

    // each wave computes 16 rows: 4 groups of 4 rows in flight
    for (int g2 = 0; g2 < 4; g2++) {
        const int lr = wv * 16 + g2 * 4;
        const float* b0 = &xs[(lr + 0) * K];
        const float* b1 = &xs[(lr + 1) * K];
        const float* b2 = &xs[(lr + 2) * K];
        const float* b3 = &xs[(lr + 3) * K];
        float a0 = 0.f, a1 = 0.f, a2 = 0.f, a3 = 0.f;
#pragma unroll
        for (int q = 0; q < K / 4; q++) {
            float4 f0 = *reinterpret_cast<const float4*>(&b0[q * 4]);
            float4 f1 = *reinterpret_cast<const float4*>(&b1[q * 4]);
            float4 f2 = *reinterpret_cast<const float4*>(&b2[q * 4]);
            float4 f3 = *reinterpret_cast<const float4*>(&b3[q * 4]);
            a0 += f0.x * wr[4 * q + 0] + f0.y * wr[4 * q + 1] + f0.z * wr[4 * q + 2] + f0.w * wr[4 * q + 3];
            a1 += f1.x * wr[4 * q + 0] + f1.y * wr[4 * q + 1] + f1.z * wr[4 * q + 2] + f1.w * wr[4 * q + 3];
            a2 += f2.x * wr[4 * q + 0] + f2.y * wr[4 * q + 1] + f2.z * wr[4 * q + 2] + f2.w * wr[4 * q + 3];
            a3 += f3.x * wr[4 * q + 0] + f3.y * wr[4 * q + 1] + f3.z * wr[4 * q + 2] + f3.w * wr[4 * q + 3];
        }
        // attention logits (full-wave butterfly; result valid in all lanes)
        float s0 = a0 * asl, d0 = a0 * adl;
        float s1 = a1 * asl, d1 = a1 * adl;
        float s2 = a2 * asl, d2 = a2 * adl;
        float s3 = a3 * asl, d3 = a3 * adl;
#pragma unroll
        for (int o = 32; o; o >>= 1) {
            s0 += __shfl_xor(s0, o); d0 += __shfl_xor(d0, o);
            s1 += __shfl_xor(s1, o); d1 += __shfl_xor(d1, o);
            s2 += __shfl_xor(s2, o); d2 += __shfl_xor(d2, o);
            s3 += __shfl_xor(s3, o); d3 += __shfl_xor(d3, o);
        }
        const int r0 = row0 + lr;
        if (r0 + 0 < n) h[(size_t)(r0 + 0) * 64 + lane] = a0;
        if (r0 + 1 < n) h[(size_t)(r0 + 1) * 64 + lane] = a1;
        if (r0 + 2 < n) h[(size_t)(r0 + 2) * 64 + lane] = a2;
        if (r0 + 3 < n) h[(size_t)(r0 + 3) * 64 + lane] = a3;
        if (lane == 0) {
            if (r0 + 0 < n) { esrc[r0 + 0] = s0; edst[r0 + 0] = d0; }
            if (r0 + 1 < n) { esrc[r0 + 1] = s1; edst[r0 + 1] = d1; }
            if (r0 + 2 < n) { esrc[r0 + 2] = s2; edst[r0 + 2] = d2; }
            if (r0 + 3 < n) { esrc[r0 + 3] = s3; edst[r0 + 3] = d3; }
        }
    }
}

// ---------------- Per-layer: softmax + aggregate (one wave per dst) ----------------

#define GATHER8(J)                                                                  \
    {                                                                               \
        float w0 = __shfl(w, (J) + 0), w1 = __shfl(w, (J) + 1);                     \
        float w2 = __shfl(w, (J) + 2), w3 = __shfl(w, (J) + 3);                     \
        float w4_ = __shfl(w, (J) + 4), w5 = __shfl(w, (J) + 5);                    \
        float w6 = __shfl(w, (J) + 6), w7 = __shfl(w, (J) + 7);                     \
        int s0 = __shfl(sN, (J) + 0), s1 = __shfl(sN, (J) + 1);                     \
        int s2 = __shfl(sN, (J) + 2), s3 = __shfl(sN, (J) + 3);                     \
        int s4 = __shfl(sN, (J) + 4), s5 = __shfl(sN, (J) + 5);                     \
        int s6 = __shfl(sN, (J) + 6), s7 = __shfl(sN, (J) + 7);                     \
        float g0 = h[(size_t)s0 * 64 + lane], g1 = h[(size_t)s1 * 64 + lane];       \
        float g2 = h[(size_t)s2 * 64 + lane], g3 = h[(size_t)s3 * 64 + lane];       \
        float g4 = h[(size_t)s4 * 64 + lane], g5 = h[(size_t)s5 * 64 + lane];       \
        float g6 = h[(size_t)s6 * 64 + lane], g7 = h[(size_t)s7 * 64 + lane];       \
        acc += w0 * g0; acc += w1 * g1; acc += w2 * g2; acc += w3 * g3;             \
        acc += w4_ * g4; acc += w5 * g5; acc += w6 * g6; acc += w7 * g7;            \
    }

__global__ __launch_bounds__(256) void gat_aggregate_kernel(
        const float* __restrict__ h, const float* __restrict__ esrc, const float* __restrict__ edst,
        const int* __restrict__ rowptr, const int* __restrict__ csr_src,
        const float* __restrict__ bias, int n, int do_relu, float* __restrict__ out) {
    int wave = threadIdx.x >> 6, lane = threadIdx.x & 63;
    for (int dst = blockIdx.x * 4 + wave; dst < n; dst += gridDim.x * 4) {
        int rs = rowptr[dst], re = rowptr[dst + 1];
        int deg = re - rs;
        float ed = edst[dst];
        float eself = leaky(esrc[dst] + ed);
        float acc;
        if (deg <= 64) {
            int i = rs + lane;
            bool valid = i < re;
            int sN = valid ? csr_src[i] : 0;
            float e = valid ? leaky(esrc[sN] + ed) : -1e30f;
            float m = fmaxf(e, eself);
#pragma unroll
            for (int off = 32; off; off >>= 1) m = fmaxf(m, __shfl_xor(m, off));
            float p = valid ? expf(e - m) : 0.f;
            float s = p;
#pragma unroll
            for (int off = 32; off; off >>= 1) s += __shfl_xor(s, off);
            float pself = expf(eself - m);
            s += pself;
            float inv_s = 1.f / s;
            acc = pself * inv_s * h[(size_t)dst * 64 + lane];
            float w = p * inv_s;
            int j = 0;
            for (; j + 8 <= deg; j += 8) GATHER8(j);
            for (; j < deg; j++) {
                float wj = __shfl(w, j);
                int sj = __shfl(sN, j);
                acc += wj * h[(size_t)sj * 64 + lane];
            }
        } else {
            float m = eself, s = (lane == 0) ? 1.f : 0.f;
            for (int i = rs + lane; i < re; i += 64) {
                int sN = csr_src[i];
                float e = leaky(esrc[sN] + ed);
                float nm = fmaxf(m, e);
                s = s * expf(m - nm) + expf(e - nm);
                m = nm;
            }
#pragma unroll
            for (int off = 32; off; off >>= 1) {
                float m2 = __shfl_xor(m, off), s2 = __shfl_xor(s, off);
                float nm = fmaxf(m, m2);
                s = s * expf(m - nm) + s2 * expf(m2 - nm);
                m = nm;
            }
            float inv_s = 1.f / s;
            acc = expf(eself - m) * inv_s * h[(size_t)dst * 64 + lane];
            for (int base = rs; base < re; base += 64) {
                int i = base + lane;
                int sN = 0;
                float w = 0.f;
                if (i < re) {
                    sN = csr_src[i];
                    w = expf(leaky(esrc[sN] + ed) - m) * inv_s;
                }
                int cnt = min(64, re - base);
                int j = 0;
                for (; j + 8 <= cnt; j += 8) GATHER8(j);
                for (; j < cnt; j++) {
                    float wj = __shfl(w, j);
                    int sj = __shfl(sN, j);
                    acc += wj * h[(size_t)sj * 64 + lane];
                }
            }
        }
        float v = acc + bias[lane];
        if (do_relu) v = fmaxf(v, 0.f);
        out[(size_t)dst * 64 + lane] = v;
    }
}

// ---------------- launch ----------------

extern "C" void kernel_launch(void* const* d_in, const int* in_sizes, int n_in,
                              void* d_out, int out_size, void* d_ws, size_t ws_size,
                              hipStream_t stream) {
    const float* x = (const float*)d_in[0];
    const int* ei = (const int*)d_in[1];   // harness stages integer inputs as int32
    const float* W1 = (const float*)d_in[2];
    const float* as1 = (const float*)d_in[3];
    const float* ad1 = (const float*)d_in[4];
    const float* b1 = (const float*)d_in[5];
    const float* W2 = (const float*)d_in[6];
    const float* as2 = (const float*)d_in[7];
    const float* ad2 = (const float*)d_in[8];
    const float* b2 = (const float*)d_in[9];
    const float* W3 = (const float*)d_in[10];
    const float* as3 = (const float*)d_in[11];
    const float* ad3 = (const float*)d_in[12];
    const float* b3 = (const float*)d_in[13];

    const int FIN = 128, HID = 64;
    int N = in_sizes[0] / FIN;
    int E = in_sizes[1] / 2;
    int nbin = (N + BINW - 1) >> SH;          // 196 for N=100k (must be <= 256)

    char* base = (char*)d_ws;
    size_t off = 0;
    auto alloc = [&](size_t bytes) -> void* {
        void* p = base + off;
        off = (off + bytes + 255) & ~(size_t)255;
        return p;
    };
    int* rowptr = (int*)alloc((size_t)(N + 1) * 4);
    int* bin_cnt = (int*)alloc((size_t)nbin * 4);
    int* bin_base = (int*)alloc((size_t)(nbin + 1) * 4);
    int* bin_cur = (int*)alloc((size_t)nbin * 4);
    int* csr_src = (int*)alloc((size_t)E * 4);
    float* esrc = (float*)alloc((size_t)N * 4);
    float* edst = (float*)alloc((size_t)N * 4);
    float* hA = (float*)alloc((size_t)N * HID * 4);
    unsigned* staged = (unsigned*)hA;   // alias: staging is dead before first gemm writes hA
    (void)ws_size;
    (void)n_in;

    float* out = (float*)d_out;   // doubles as the ping buffer between layers

    // ---- CSR build (graph identical across the 3 layers; no per-dst global atomics) ----
    zero_int_kernel<<<1, 256, 0, stream>>>(bin_cnt, nbin);
    histo_bins_kernel<<<2048, 256, 0, stream>>>(ei + E, E, bin_cnt);
    scan_bins_kernel<<<1, 256, 0, stream>>>(bin_cnt, nbin, bin_base, bin_cur);
    bin_sort_kernel<<<(E + TILE - 1) / TILE, 256, 0, stream>>>(ei, E, nbin, bin_cur, staged);
    bin_finalize_kernel<<<nbin, 512, 0, stream>>>(staged, bin_base, N, rowptr, csr_src);

    int agrid = (N + 3) / 4;
    int ggrid = (N + 63) / 64;   // one 64-row tile per block

    // layer 1: x -> hA -> out (relu)
    gemm_logits_kernel<128><<<ggrid, 256, 0, stream>>>(x, W1, as1, ad1, N, hA, esrc, edst);
    gat_aggregate_kernel<<<agrid, 256, 0, stream>>>(hA, esrc, edst, rowptr, csr_src, b1, N, 1, out);
    // layer 2: out -> hA -> out (relu)
    gemm_logits_kernel<64><<<ggrid, 256, 0, stream>>>(out, W2, as2, ad2, N, hA, esrc, edst);
    gat_aggregate_kernel<<<agrid, 256, 0, stream>>>(hA, esrc, edst, rowptr, csr_src, b2, N, 1, out);
    // layer 3: out -> hA -> out (no relu)
    gemm_logits_kernel<64><<<ggrid, 256, 0, stream>>>(out, W3, as3, ad3, N, hA, esrc, edst);
    gat_aggregate_kernel<<<agrid, 256, 0, stream>>>(hA, esrc, edst, rowptr, csr_src, b3, N, 0, out);
}